// Round 6
// baseline (198.648 us; speedup 1.0000x reference)
//
#include <hip/hip_runtime.h>
#include <stdint.h>

static constexpr int Kdim  = 1024;    // L
static constexpr int Ncols = 512;     // OUT

typedef __attribute__((ext_vector_type(8))) short bf16x8;
typedef __attribute__((ext_vector_type(4))) float f32x4;

__device__ __forceinline__ unsigned short f2bf(float f) {
  unsigned u = __builtin_bit_cast(unsigned, f);
  u += 0x7FFFu + ((u >> 16) & 1u);          // RNE
  return (unsigned short)(u >> 16);
}
__device__ __forceinline__ unsigned f2bf2(float lo, float hi) {
  unsigned ul = __builtin_bit_cast(unsigned, lo);
  unsigned uh = __builtin_bit_cast(unsigned, hi);
  ul += 0x7FFFu + ((ul >> 16) & 1u);
  uh += 0x7FFFu + ((uh >> 16) & 1u);
  return (ul >> 16) | (uh & 0xFFFF0000u);
}
__device__ __forceinline__ bf16x8 pack8(float4 a, float4 b) {
  union { unsigned u[4]; bf16x8 v; } r;
  r.u[0] = f2bf2(a.x, a.y); r.u[1] = f2bf2(a.z, a.w);
  r.u[2] = f2bf2(b.x, b.y); r.u[3] = f2bf2(b.z, b.w);
  return r.v;
}

// ---------------------------------------------------------------------------
// prep_w: 512 blocks: Wt[n][k] = bf16(0.5*(W_in+W_out)+W_root)^T.  ~7 MiB.
// Also warms Wt into L2 for the gemm.
// ---------------------------------------------------------------------------
__global__ __launch_bounds__(256) void prep_w(
    const float* __restrict__ Win, const float* __restrict__ Wout,
    const float* __restrict__ Wroot, unsigned short* __restrict__ Wt)
{
  __shared__ unsigned short lds[32 * 36];
  const int t  = threadIdx.x;
  const int b2 = blockIdx.x;
  const int tk0 = (b2 & 31) * 32;
  const int tn0 = (b2 >> 5) * 32;
  {
    const int k  = t >> 3;
    const int nq = (t & 7) * 4;
    const int gi = (tk0 + k) * Ncols + tn0 + nq;
    const float4 wi = *(const float4*)(Win + gi);
    const float4 wo = *(const float4*)(Wout + gi);
    const float4 wr = *(const float4*)(Wroot + gi);
    lds[(nq + 0) * 36 + k] = f2bf(0.5f * (wi.x + wo.x) + wr.x);
    lds[(nq + 1) * 36 + k] = f2bf(0.5f * (wi.y + wo.y) + wr.y);
    lds[(nq + 2) * 36 + k] = f2bf(0.5f * (wi.z + wo.z) + wr.z);
    lds[(nq + 3) * 36 + k] = f2bf(0.5f * (wi.w + wo.w) + wr.w);
  }
  __syncthreads();
  {
    const int n  = t >> 3;
    const int k8 = (t & 7) * 4;
    const ushort4 v = *(const ushort4*)&lds[n * 36 + k8];
    *(ushort4*)(Wt + (size_t)(tn0 + n) * Kdim + tk0 + k8) = v;
  }
}

// ---------------------------------------------------------------------------
// gemm_direct: Y = bf16(x) @ Wt^T + bias.  REGIME CHANGE: no LDS, no
// barriers, no global_load_lds.  Both operands load straight to registers
// in MFMA fragment layout (per-lane 16 B):
//   A-frag i: lane(quad,lm) reads x[m0 + i*16 + lm][kk*32 + quad*8 .. +7]
//             (2x dwordx4 f32, converted in-register via f2bf2)
//   B-frag j: lane reads Wt[n0 + j*16 + lm][kk*32 + quad*8 .. +7] (1x dwordx4)
// Wave = 64m x 64n output (acc 4x4 f32x4 = 64 VGPR, 16 MFMA / k-step).
// Block = 4 waves, SAME 64 m-rows, n0 = nhalf*256 + w*64 -> the 4 waves'
// x reads are L1-broadcast; Wt (1 MB) is L2-resident.
// Grid 512: panel = bid&255, nhalf = bid>>8 -> the 2 x-sharers (bid, bid+256)
// land on the SAME XCD (%8) -> x read from HBM once.
// Pipeline: 2 register sets P/Q ping-pong, 2-deep prefetch; convert-first
// frees a set's f32 regs before its reload.  Waves free-run: latency is
// hidden per-wave (24 KB in flight/wave), never amplified by a barrier convoy.
// ---------------------------------------------------------------------------
__global__ __launch_bounds__(256, 2) void gemm_direct(
    const float* __restrict__ x, const unsigned short* __restrict__ Wt,
    const float* __restrict__ b_in, const float* __restrict__ b_out,
    const float* __restrict__ b_root, float* __restrict__ Y)
{
  const int bid   = blockIdx.x;
  const int panel = bid & 255;               // 64-row m-panel
  const int nhalf = bid >> 8;                // 0/1
  const int m0    = panel * 64;

  const int t    = threadIdx.x;
  const int lane = t & 63;
  const int w    = t >> 6;
  const int n0   = nhalf * 256 + w * 64;
  const int quad = lane >> 4;
  const int lm   = lane & 15;

  const float*          gA = x  + (size_t)(m0 + lm) * Kdim + quad * 8;
  const unsigned short* gB = Wt + (size_t)(n0 + lm) * Kdim + quad * 8;
  constexpr size_t AROW = (size_t)16 * Kdim;   // +16 rows (elements)

  f32x4 acc[4][4] = {};

  // register sets P/Q: 4 A-frags as raw f32 (8x float4) + 4 B-frags (bf16x8)
  float4 PA0a, PA0b, PA1a, PA1b, PA2a, PA2b, PA3a, PA3b;
  float4 QA0a, QA0b, QA1a, QA1b, QA2a, QA2b, QA3a, QA3b;
  bf16x8 PB0, PB1, PB2, PB3, QB0, QB1, QB2, QB3;

#define LOADSET(S, KK) do {                                               \
    const float* a_ = gA + (size_t)(KK) * 32;                             \
    S##A0a = *(const float4*)(a_);            S##A0b = *(const float4*)(a_ + 4); \
    S##A1a = *(const float4*)(a_ + AROW);     S##A1b = *(const float4*)(a_ + AROW + 4); \
    S##A2a = *(const float4*)(a_ + 2 * AROW); S##A2b = *(const float4*)(a_ + 2 * AROW + 4); \
    S##A3a = *(const float4*)(a_ + 3 * AROW); S##A3b = *(const float4*)(a_ + 3 * AROW + 4); \
    const unsigned short* b_ = gB + (size_t)(KK) * 32;                    \
    S##B0 = *(const bf16x8*)(b_);                                         \
    S##B1 = *(const bf16x8*)(b_ + AROW);                                  \
    S##B2 = *(const bf16x8*)(b_ + 2 * AROW);                              \
    S##B3 = *(const bf16x8*)(b_ + 3 * AROW);                              \
  } while (0)

#define BODY(S, LDKK) do {                                                \
    bf16x8 af0 = pack8(S##A0a, S##A0b);                                   \
    bf16x8 af1 = pack8(S##A1a, S##A1b);                                   \
    bf16x8 af2 = pack8(S##A2a, S##A2b);                                   \
    bf16x8 af3 = pack8(S##A3a, S##A3b);                                   \
    bf16x8 bf0 = S##B0, bf1 = S##B1, bf2 = S##B2, bf3 = S##B3;            \
    if ((LDKK) >= 0) LOADSET(S, LDKK);  /* set's old regs dead: reload */ \
    acc[0][0] = __builtin_amdgcn_mfma_f32_16x16x32_bf16(af0, bf0, acc[0][0], 0, 0, 0); \
    acc[0][1] = __builtin_amdgcn_mfma_f32_16x16x32_bf16(af0, bf1, acc[0][1], 0, 0, 0); \
    acc[0][2] = __builtin_amdgcn_mfma_f32_16x16x32_bf16(af0, bf2, acc[0][2], 0, 0, 0); \
    acc[0][3] = __builtin_amdgcn_mfma_f32_16x16x32_bf16(af0, bf3, acc[0][3], 0, 0, 0); \
    acc[1][0] = __builtin_amdgcn_mfma_f32_16x16x32_bf16(af1, bf0, acc[1][0], 0, 0, 0); \
    acc[1][1] = __builtin_amdgcn_mfma_f32_16x16x32_bf16(af1, bf1, acc[1][1], 0, 0, 0); \
    acc[1][2] = __builtin_amdgcn_mfma_f32_16x16x32_bf16(af1, bf2, acc[1][2], 0, 0, 0); \
    acc[1][3] = __builtin_amdgcn_mfma_f32_16x16x32_bf16(af1, bf3, acc[1][3], 0, 0, 0); \
    acc[2][0] = __builtin_amdgcn_mfma_f32_16x16x32_bf16(af2, bf0, acc[2][0], 0, 0, 0); \
    acc[2][1] = __builtin_amdgcn_mfma_f32_16x16x32_bf16(af2, bf1, acc[2][1], 0, 0, 0); \
    acc[2][2] = __builtin_amdgcn_mfma_f32_16x16x32_bf16(af2, bf2, acc[2][2], 0, 0, 0); \
    acc[2][3] = __builtin_amdgcn_mfma_f32_16x16x32_bf16(af2, bf3, acc[2][3], 0, 0, 0); \
    acc[3][0] = __builtin_amdgcn_mfma_f32_16x16x32_bf16(af3, bf0, acc[3][0], 0, 0, 0); \
    acc[3][1] = __builtin_amdgcn_mfma_f32_16x16x32_bf16(af3, bf1, acc[3][1], 0, 0, 0); \
    acc[3][2] = __builtin_amdgcn_mfma_f32_16x16x32_bf16(af3, bf2, acc[3][2], 0, 0, 0); \
    acc[3][3] = __builtin_amdgcn_mfma_f32_16x16x32_bf16(af3, bf3, acc[3][3], 0, 0, 0); \
  } while (0)

  // prologue: 2 k-steps in flight
  LOADSET(P, 0);
  LOADSET(Q, 1);

  #pragma unroll 1
  for (int kk = 0; kk < 28; kk += 2) {
    BODY(P, kk + 2);
    BODY(Q, kk + 3);
  }
  BODY(P, 30);
  BODY(Q, 31);
  BODY(P, -1);        // kk=30, no reload
  BODY(Q, -1);        // kk=31, no reload

#undef BODY
#undef LOADSET

  // epilogue: D[row=quad*4+r][col=lm] per 16x16 tile; bias fused
  #pragma unroll
  for (int j = 0; j < 4; ++j) {
    const int gc = n0 + j * 16 + lm;
    const float bias = 0.5f * (b_in[gc] + b_out[gc]) + b_root[gc];
    #pragma unroll
    for (int i = 0; i < 4; ++i) {
      const int gr = m0 + i * 16 + quad * 4;
      float* yp = Y + (size_t)gr * Ncols + gc;
      #pragma unroll
      for (int r = 0; r < 4; ++r)
        yp[(size_t)r * Ncols] = acc[i][j][r] + bias;
    }
  }
}

// ---------------------------------------------------------------------------
extern "C" void kernel_launch(void* const* d_in, const int* in_sizes, int n_in,
                              void* d_out, int out_size, void* d_ws, size_t ws_size,
                              hipStream_t stream)
{
  const float* x      = (const float*)d_in[0];
  // d_in[1] = At : dead input (ChebConv K=1 -> no neighbor aggregation)
  const float* W_in   = (const float*)d_in[2];
  const float* b_in   = (const float*)d_in[3];
  const float* W_out  = (const float*)d_in[4];
  const float* b_out  = (const float*)d_in[5];
  const float* W_root = (const float*)d_in[6];
  const float* b_root = (const float*)d_in[7];
  float* y = (float*)d_out;

  unsigned short* Wt = (unsigned short*)d_ws;   // 1 MiB only

  prep_w<<<dim3(512), dim3(256), 0, stream>>>(W_in, W_out, W_root, Wt);
  gemm_direct<<<dim3(512), dim3(256), 0, stream>>>(x, Wt, b_in, b_out, b_root, y);
}

// Round 9
// 166.837 us; speedup vs baseline: 1.1907x; 1.1907x over previous
//
#include <hip/hip_runtime.h>
#include <stdint.h>

static constexpr int Mrows = 16384;   // B*N = 64*256
static constexpr int Kdim  = 1024;    // L
static constexpr int Ncols = 512;     // OUT

typedef __attribute__((ext_vector_type(8))) short bf16x8;
typedef __attribute__((ext_vector_type(4))) float f32x4;

__device__ __forceinline__ unsigned short f2bf(float f) {
  unsigned u = __builtin_bit_cast(unsigned, f);
  u += 0x7FFFu + ((u >> 16) & 1u);          // RNE
  return (unsigned short)(u >> 16);
}
__device__ __forceinline__ unsigned f2bf2(float lo, float hi) {
  unsigned ul = __builtin_bit_cast(unsigned, lo);
  unsigned uh = __builtin_bit_cast(unsigned, hi);
  ul += 0x7FFFu + ((ul >> 16) & 1u);
  uh += 0x7FFFu + ((uh >> 16) & 1u);
  return (ul >> 16) | (uh & 0xFFFF0000u);
}

// async global->LDS, 16B per lane; LDS dest = WAVE-UNIFORM base + lane*16,
// swizzle goes on the per-lane GLOBAL source address
__device__ __forceinline__ void gl2lds16(const void* g, void* l) {
  __builtin_amdgcn_global_load_lds(
      (const __attribute__((address_space(1))) void*)g,
      (__attribute__((address_space(3))) void*)l, 16, 0, 0);
}

// ---------------------------------------------------------------------------
// prep (verbatim R0 structure, the fastest measured):
//   blocks [0,8192)   : Xbf = bf16(x)  (8 floats / thread, pure streaming)
//   blocks [8192,8704): Wt[n][k] = bf16(0.5*(W_in+W_out)+W_root)^T
// ---------------------------------------------------------------------------
__global__ __launch_bounds__(256) void prep(
    const float* __restrict__ x,
    const float* __restrict__ Win, const float* __restrict__ Wout,
    const float* __restrict__ Wroot,
    unsigned short* __restrict__ Xbf, unsigned short* __restrict__ Wt)
{
  const int bid = blockIdx.x;
  const int t = threadIdx.x;
  if (bid < 8192) {
    const size_t base = ((size_t)bid * 256 + t) * 8;
    const float4 v0 = *(const float4*)(x + base);
    const float4 v1 = *(const float4*)(x + base + 4);
    uint4 p;
    p.x = f2bf2(v0.x, v0.y); p.y = f2bf2(v0.z, v0.w);
    p.z = f2bf2(v1.x, v1.y); p.w = f2bf2(v1.z, v1.w);
    *(uint4*)(Xbf + base) = p;
  } else {
    __shared__ unsigned short lds[32 * 36];
    const int b2 = bid - 8192;
    const int tk0 = (b2 & 31) * 32;
    const int tn0 = (b2 >> 5) * 32;
    {
      const int k  = t >> 3;
      const int nq = (t & 7) * 4;
      const int gi = (tk0 + k) * Ncols + tn0 + nq;
      const float4 wi = *(const float4*)(Win + gi);
      const float4 wo = *(const float4*)(Wout + gi);
      const float4 wr = *(const float4*)(Wroot + gi);
      lds[(nq + 0) * 36 + k] = f2bf(0.5f * (wi.x + wo.x) + wr.x);
      lds[(nq + 1) * 36 + k] = f2bf(0.5f * (wi.y + wo.y) + wr.y);
      lds[(nq + 2) * 36 + k] = f2bf(0.5f * (wi.z + wo.z) + wr.z);
      lds[(nq + 3) * 36 + k] = f2bf(0.5f * (wi.w + wo.w) + wr.w);
    }
    __syncthreads();
    {
      const int n  = t >> 3;
      const int k8 = (t & 7) * 4;
      const ushort4 v = *(const ushort4*)&lds[n * 36 + k8];
      *(ushort4*)(Wt + (size_t)(tn0 + n) * Kdim + tk0 + k8) = v;
    }
  }
}

// ---------------------------------------------------------------------------
// gemm_hyb: Y = Xbf @ Wt^T + bias.  Attacks the measured LDS-throughput bound
// of the R0 structure (~96 KB LDS traffic per CU-iter) by removing B from
// LDS entirely:
//   A: 64-row m-tile via global_load_lds bf16 (1 instr/wave/iter), verified
//      swizzle (slot s of row r holds chunk s^((r>>1)&3)), TRIPLE-buffered
//      (12 KB LDS), staged 2 tiles ahead.
//   B: per-lane 16 B loads from L2-resident Wt straight into registers in
//      fragment layout; one-iteration ping-pong (P/Q, statically named),
//      only 32 VGPR of prefetch state.
// Block = 64m x 256n, 4 waves, wave = 64x64 output (4x4 acc, 16 MFMA/iter).
// Grid 512 = 2 blocks/CU.  LDS traffic/CU-iter: 32 KB reads + 8 KB writes
// (was ~96 KB).
//
// vmcnt invariant (per wave, in-order queue):
//   at iter entry: [A(t+1), B(t)x4] = 5 outstanding
//   issue A(t+2), B(t+1)x4 -> 10; compiler's wait for B(t) regs at the MFMA
//   drains to 5 (also lands A(t+1)); explicit vmcnt(5)+s_barrier at iter end
//   leaves exactly [A(t+2), B(t+1)x4].  Buffer written at iter t (b2_) is the
//   buffer read at t-1, whose ds_reads were consumed before that barrier.
// ---------------------------------------------------------------------------
__global__ __launch_bounds__(256, 2) void gemm_hyb(
    const unsigned short* __restrict__ Xbf, const unsigned short* __restrict__ Wt,
    const float* __restrict__ b_in, const float* __restrict__ b_out,
    const float* __restrict__ b_root, float* __restrict__ Y)
{
  constexpr int ABUF = 64 * 32;              // shorts per A buffer (4 KB)
  __shared__ __attribute__((aligned(16))) short As[3 * ABUF];

  const int bid = blockIdx.x;
  const int m0  = (bid >> 1) * 64;
  const int nh  = bid & 1;

  const int t    = threadIdx.x;
  const int lane = t & 63;
  const int w    = t >> 6;
  const int quad = lane >> 4;
  const int lm   = lane & 15;
  const int nw   = nh * 256 + w * 64;        // this wave's n-origin

  // --- A staging: wave w stages rows w*16..w*16+15 (one 1-KB gl2lds).
  const int sr = lane >> 2;
  const int ss = lane & 3;
  const int sc = ss ^ ((sr >> 1) & 3);
  const unsigned short* gA = Xbf + (size_t)(m0 + w * 16 + sr) * Kdim + sc * 8;
  short* const lA = &As[w * 512];            // wave-uniform base; +buf*ABUF

  // --- B per-lane: frag j, lane(quad,lm) reads Wt[nw + j*16 + lm][kk*32+quad*8]
  const unsigned short* gB = Wt + (size_t)(nw + lm) * Kdim + quad * 8;
  constexpr size_t BROW = (size_t)16 * Kdim; // +16 n-rows (elements)

  // --- A fragment read offset (verified swizzled layout)
  const int aoff = lm * 32 + (quad ^ ((lm >> 1) & 3)) * 8;   // + i*512

  f32x4 acc[4][4] = {};
  bf16x8 PB0, PB1, PB2, PB3, QB0, QB1, QB2, QB3;

#define LOADB(S, KK) do {                                                 \
    const unsigned short* b_ = gB + (size_t)(KK) * 32;                    \
    S##B0 = *(const bf16x8*)(b_);                                         \
    S##B1 = *(const bf16x8*)(b_ + BROW);                                  \
    S##B2 = *(const bf16x8*)(b_ + 2 * BROW);                              \
    S##B3 = *(const bf16x8*)(b_ + 3 * BROW);                              \
  } while (0)

#define BODY(TT, S, R) do {                                               \
    /* stage A(t+2) first (oldest in vm queue), then B(t+1) */            \
    { int ta_ = (TT) + 2; if (ta_ > 31) ta_ = 31;                         \
      gl2lds16(gA + ta_ * 32, lA + b2_ * ABUF); }                         \
    __builtin_amdgcn_sched_barrier(0);                                    \
    { int tb_ = (TT) + 1; if (tb_ > 31) tb_ = 31;                         \
      LOADB(R, tb_); }                                                    \
    bf16x8 af[4];                                                         \
    _Pragma("unroll") for (int i = 0; i < 4; ++i)                         \
      af[i] = *(const bf16x8*)&As[b0_ * ABUF + aoff + i * 512];           \
    _Pragma("unroll") for (int i = 0; i < 4; ++i) {                       \
      acc[i][0] = __builtin_amdgcn_mfma_f32_16x16x32_bf16(af[i], S##B0, acc[i][0], 0, 0, 0); \
      acc[i][1] = __builtin_amdgcn_mfma_f32_16x16x32_bf16(af[i], S##B1, acc[i][1], 0, 0, 0); \
      acc[i][2] = __builtin_amdgcn_mfma_f32_16x16x32_bf16(af[i], S##B2, acc[i][2], 0, 0, 0); \
      acc[i][3] = __builtin_amdgcn_mfma_f32_16x16x32_bf16(af[i], S##B3, acc[i][3], 0, 0, 0); \
    }                                                                     \
    asm volatile("s_waitcnt vmcnt(5)" ::: "memory");                      \
    __builtin_amdgcn_s_barrier();                                         \
    __builtin_amdgcn_sched_barrier(0);                                    \
    { const int r_ = b0_; b0_ = b1_; b1_ = b2_; b2_ = r_; }               \
  } while (0)

  // prologue (clean): A(0)->buf0, A(1)->buf1, B(0)->P.
  // Queue = [A0, A1, B0x4] = 6; vmcnt(5) -> A(0) landed; barrier.
  gl2lds16(gA,      lA);
  gl2lds16(gA + 32, lA + ABUF);
  __builtin_amdgcn_sched_barrier(0);
  LOADB(P, 0);
  asm volatile("s_waitcnt vmcnt(5)" ::: "memory");
  __builtin_amdgcn_s_barrier();
  __builtin_amdgcn_sched_barrier(0);

  int b0_ = 0, b1_ = 1, b2_ = 2;
  #pragma unroll 1
  for (int it = 0; it < 32; it += 2) {
    BODY(it,     P, Q);
    BODY(it + 1, Q, P);
  }
  asm volatile("s_waitcnt vmcnt(0)" ::: "memory");

#undef BODY
#undef LOADB

  // epilogue: D[row=quad*4+r][col=lm] per 16x16 tile; bias fused
  #pragma unroll
  for (int j = 0; j < 4; ++j) {
    const int gc = nw + j * 16 + lm;
    const float bias = 0.5f * (b_in[gc] + b_out[gc]) + b_root[gc];
    #pragma unroll
    for (int i = 0; i < 4; ++i) {
      const int gr = m0 + i * 16 + quad * 4;
      float* yp = Y + (size_t)gr * Ncols + gc;
      #pragma unroll
      for (int r = 0; r < 4; ++r)
        yp[(size_t)r * Ncols] = acc[i][j][r] + bias;
    }
  }
}

// ---------------------------------------------------------------------------
extern "C" void kernel_launch(void* const* d_in, const int* in_sizes, int n_in,
                              void* d_out, int out_size, void* d_ws, size_t ws_size,
                              hipStream_t stream)
{
  const float* x      = (const float*)d_in[0];
  // d_in[1] = At : dead input (ChebConv K=1 -> no neighbor aggregation)
  const float* W_in   = (const float*)d_in[2];
  const float* b_in   = (const float*)d_in[3];
  const float* W_out  = (const float*)d_in[4];
  const float* b_out  = (const float*)d_in[5];
  const float* W_root = (const float*)d_in[6];
  const float* b_root = (const float*)d_in[7];
  float* y = (float*)d_out;

  unsigned short* Xbf = (unsigned short*)d_ws;                        // 32 MiB
  unsigned short* Wt  = (unsigned short*)d_ws + (size_t)Mrows * Kdim; // 1 MiB

  prep<<<dim3(8192 + 512), dim3(256), 0, stream>>>(x, W_in, W_out, W_root, Xbf, Wt);
  gemm_hyb<<<dim3(512), dim3(256), 0, stream>>>(Xbf, Wt, b_in, b_out, b_root, y);
}